// Round 6
// baseline (611.767 us; speedup 1.0000x reference)
//
#include <hip/hip_runtime.h>
#include <stdint.h>

#define NDIM 512
#define CDIM 128
#define MDIM (NDIM*NDIM)   // 262144

typedef unsigned short u16;
typedef __bf16 bf16v8 __attribute__((ext_vector_type(8)));
typedef float f32x4 __attribute__((ext_vector_type(4)));
typedef short s16x4 __attribute__((ext_vector_type(4)));

__device__ __forceinline__ u16 f2bf(float f){
  union { float f; uint32_t u; } v; v.f = f;
  uint32_t u = v.u;
  u += 0x7fffu + ((u >> 16) & 1u);   // round-to-nearest-even
  return (u16)(u >> 16);
}
__device__ __forceinline__ float bf2f(u16 h){
  union { uint32_t u; float f; } v; v.u = ((uint32_t)h) << 16;
  return v.f;
}
__device__ __forceinline__ float sigm(float x){
  return __builtin_amdgcn_rcpf(1.0f + __expf(-x));
}
__device__ __forceinline__ f32x4 mfma_bf16(bf16v8 a, bf16v8 b, f32x4 c){
  return __builtin_amdgcn_mfma_f32_16x16x32_bf16(a, b, c, 0, 0, 0);
}

// ---------------------------------------------------------------------------
// K0: pack weights transposed to bf16. wt[d][k], d in [0,768):
//   d<256: w_proj[:,d] ; d<512: w_gate[:,d-256] ; d<640: w_gate_out[:,d-512]
//   d>=640: w_out[:,d-640]
// ---------------------------------------------------------------------------
__global__ void k0_prep(const float* __restrict__ wp, const float* __restrict__ wg,
                        const float* __restrict__ wgo, const float* __restrict__ wo,
                        u16* __restrict__ wt){
  const int d = blockIdx.x, k = threadIdx.x;
  float v;
  if (d < 256)      v = wp[k*256 + d];
  else if (d < 512) v = wg[k*256 + (d-256)];
  else if (d < 640) v = wgo[k*128 + (d-512)];
  else              v = wo[k*128 + (d-640)];
  wt[d*CDIM + k] = f2bf(v);
}

// ---------------------------------------------------------------------------
// K1: R0 structure, no gate phase. Chunked XCD swizzle.
// ---------------------------------------------------------------------------
__global__ __launch_bounds__(256) void k1_ln_proj(
    const float* __restrict__ act, const float* __restrict__ mask,
    const float* __restrict__ lns, const float* __restrict__ lno,
    const u16* __restrict__ wt, u16* __restrict__ AB)
{
  __shared__ __align__(16) u16 xs[64][136];    // pitch 272B: 2-way bank alias (free)
  __shared__ __align__(16) u16 pgs[256][72];   // [d][m], pitch 144B
  __shared__ float msk[64];
  const int t = threadIdx.x;
  const int blk = ((int)blockIdx.x & 7)*512 + ((int)blockIdx.x >> 3);  // 4096%8==0
  const int m0 = blk * 64;

  { // Phase 1: layernorm, 4 threads per row
    const int r = t >> 2, q = t & 3;
    const float4* rp = (const float4*)(act + (size_t)(m0 + r)*CDIM + q*32);
    float4 v[8];
    #pragma unroll
    for (int i = 0; i < 8; ++i) v[i] = rp[i];
    float s = 0.f, s2 = 0.f;
    #pragma unroll
    for (int i = 0; i < 8; ++i){
      s  += v[i].x + v[i].y + v[i].z + v[i].w;
      s2 += v[i].x*v[i].x + v[i].y*v[i].y + v[i].z*v[i].z + v[i].w*v[i].w;
    }
    s += __shfl_xor(s, 1);  s2 += __shfl_xor(s2, 1);
    s += __shfl_xor(s, 2);  s2 += __shfl_xor(s2, 2);
    const float mean = s * (1.f/128.f);
    const float rstd = rsqrtf(s2 * (1.f/128.f) - mean*mean + 1e-5f);
    const float4* lsp = (const float4*)(lns + q*32);
    const float4* lop = (const float4*)(lno + q*32);
    #pragma unroll
    for (int i = 0; i < 8; ++i){
      const float4 sc = lsp[i], of = lop[i];
      s16x4 pk;
      pk.x = (short)f2bf((v[i].x - mean)*rstd*sc.x + of.x);
      pk.y = (short)f2bf((v[i].y - mean)*rstd*sc.y + of.y);
      pk.z = (short)f2bf((v[i].z - mean)*rstd*sc.z + of.z);
      pk.w = (short)f2bf((v[i].w - mean)*rstd*sc.w + of.w);
      *(s16x4*)&xs[r][q*32 + i*4] = pk;
    }
    if (t < 64) msk[t] = mask[m0 + t];
  }
  __syncthreads();

  const int w = t >> 6, L = t & 63, ln16 = L & 15, quad = L >> 4;
  bf16v8 af[4][4];
  #pragma unroll
  for (int rs = 0; rs < 4; ++rs)
    #pragma unroll
    for (int kk = 0; kk < 4; ++kk)
      af[rs][kk] = *(const bf16v8*)&xs[rs*16 + ln16][kk*32 + quad*8];

  const f32x4 zero4 = {0.f,0.f,0.f,0.f};
  #pragma unroll
  for (int pp = 0; pp < 4; ++pp){
    const int p = w*4 + pp;
    const u16* wpr = wt + (size_t)(16*p + ln16)*CDIM + quad*8;
    const u16* wgr = wpr + (size_t)256*CDIM;
    bf16v8 bp[4], bg[4];
    #pragma unroll
    for (int kk = 0; kk < 4; ++kk){
      bp[kk] = *(const bf16v8*)(wpr + kk*32);
      bg[kk] = *(const bf16v8*)(wgr + kk*32);
    }
    f32x4 aP[4] = {zero4, zero4, zero4, zero4};
    f32x4 aG[4] = {zero4, zero4, zero4, zero4};
    #pragma unroll
    for (int kk = 0; kk < 4; ++kk)
      #pragma unroll
      for (int rs = 0; rs < 4; ++rs){
        aP[rs] = mfma_bf16(af[rs][kk], bp[kk], aP[rs]);
        aG[rs] = mfma_bf16(af[rs][kk], bg[kk], aG[rs]);
      }
    #pragma unroll
    for (int rs = 0; rs < 4; ++rs)
      #pragma unroll
      for (int reg = 0; reg < 4; ++reg){
        const int ml = rs*16 + quad*4 + reg;          // C/D: row=quad*4+reg
        const float pg = aP[rs][reg] * sigm(aG[rs][reg]) * msk[ml];
        pgs[16*p + ln16][ml] = f2bf(pg);              // C/D: col=lane&15
      }
  }
  __syncthreads();

  #pragma unroll
  for (int p4 = 0; p4 < 4; ++p4){
    const int d = p4*64 + (t >> 2), q = t & 3;
    u16* dst = AB + (size_t)d*MDIM + m0 + q*16;
    const u16* src = &pgs[d][q*16];
    *(bf16v8*)dst       = *(const bf16v8*)src;
    *(bf16v8*)(dst + 8) = *(const bf16v8*)(src + 8);
  }
}

// ---------------------------------------------------------------------------
// K2: per-channel triangle GEMM act2[c] = a[c] @ b[c]^T. 128x128 tile, BK=64,
//     4 waves * (64x64, 4x4 accs). XCD-bijective swizzle.
// ---------------------------------------------------------------------------
__global__ __launch_bounds__(256) void k2_tri(const u16* __restrict__ AB,
                                              u16* __restrict__ act2)
{
  __shared__ __align__(16) u16 As[128][72];
  __shared__ __align__(16) u16 Bs[128][72];
  const int t = threadIdx.x;
  const int bid = ((int)blockIdx.x & 7)*256 + ((int)blockIdx.x >> 3);  // 2048%8==0
  const int c  = bid >> 4;
  const int i0 = ((bid >> 2) & 3) * 128;
  const int j0 = (bid & 3) * 128;
  const u16* Ag = AB + (size_t)(2*c)*MDIM;
  const u16* Bg = AB + (size_t)(2*c + 1)*MDIM;

  const int w = t >> 6, L = t & 63, ln16 = L & 15, quad = L >> 4;
  const int iw = (w & 1)*64, jw = (w >> 1)*64;
  const int r = t >> 1, h = t & 1;

  const f32x4 zero4 = {0.f,0.f,0.f,0.f};
  f32x4 acc[4][4];
  #pragma unroll
  for (int x = 0; x < 4; ++x)
    #pragma unroll
    for (int y = 0; y < 4; ++y) acc[x][y] = zero4;

  for (int k0 = 0; k0 < NDIM; k0 += 64){
    const u16* ga = Ag + (size_t)(i0 + r)*NDIM + k0 + h*32;
    const u16* gb = Bg + (size_t)(j0 + r)*NDIM + k0 + h*32;
    bf16v8 sa[4], sb[4];
    #pragma unroll
    for (int x = 0; x < 4; ++x){
      sa[x] = *(const bf16v8*)(ga + x*8);
      sb[x] = *(const bf16v8*)(gb + x*8);
    }
    __syncthreads();
    #pragma unroll
    for (int x = 0; x < 4; ++x){
      *(bf16v8*)&As[r][h*32 + x*8] = sa[x];
      *(bf16v8*)&Bs[r][h*32 + x*8] = sb[x];
    }
    __syncthreads();
    #pragma unroll
    for (int kk = 0; kk < 2; ++kk){
      bf16v8 ar[4], br[4];
      #pragma unroll
      for (int x = 0; x < 4; ++x) ar[x] = *(const bf16v8*)&As[iw + x*16 + ln16][kk*32 + quad*8];
      #pragma unroll
      for (int y = 0; y < 4; ++y) br[y] = *(const bf16v8*)&Bs[jw + y*16 + ln16][kk*32 + quad*8];
      #pragma unroll
      for (int x = 0; x < 4; ++x)
        #pragma unroll
        for (int y = 0; y < 4; ++y)
          acc[x][y] = mfma_bf16(ar[x], br[y], acc[x][y]);
    }
  }

  u16* op = act2 + (size_t)c*MDIM;
  #pragma unroll
  for (int x = 0; x < 4; ++x)
    #pragma unroll
    for (int y = 0; y < 4; ++y)
      #pragma unroll
      for (int reg = 0; reg < 4; ++reg){
        const int il = iw + x*16 + quad*4 + reg;
        const int jl = jw + y*16 + ln16;
        op[(size_t)(i0 + il)*NDIM + j0 + jl] = f2bf(acc[x][y][reg]);
      }
}

// ---------------------------------------------------------------------------
// K3 (R6): 4-tile software pipeline per block (T14 async-STAGE across tiles).
// Block owns 4 consecutive j-tiles of one row-panel i. Double-buffered vs.
// Per tile t: [issue gather(t+1)+act(t+1) loads] -> af(t) from LDS -> MFMA+
// store(t) -> [ds_write gather(t+1), ag(t+1) from regs] -> barrier.
// Every global load has a full compute phase to land. Gathers of the 4 tiles
// read consecutive 128-B segments of the same channel rows.
// ---------------------------------------------------------------------------
__global__ __launch_bounds__(256) void k3_out(
    const u16* __restrict__ act2, const u16* __restrict__ wt,
    const float* __restrict__ act,
    const float* __restrict__ lns, const float* __restrict__ lno,
    const float* __restrict__ cns, const float* __restrict__ cno,
    const float* __restrict__ bo, const float* __restrict__ bgo,
    float* __restrict__ out)
{
  __shared__ __align__(16) u16 vs[2][128*74];    // [buf][c*74 + jj]
  const int t = threadIdx.x;
  const int sblk = ((int)blockIdx.x & 7)*128 + ((int)blockIdx.x >> 3);  // 1024%8==0
  const int i   = sblk >> 1;          // row-panel
  const int jb0 = (sblk & 1)*4;       // first of 4 j-tiles
  const int w = t >> 6, L = t & 63, ln16 = L & 15, quad = L >> 4;
  const int cc = t >> 1, hh = t & 1;  // gather mapping: thread pair per channel
  const u16* gbase = act2 + (size_t)cc*MDIM + (size_t)i*NDIM + jb0*64 + hh*32;

  union bfu { bf16v8 v; u16 u[8]; };
  bf16v8 ag[2][4];     // gate A-fragments, ping-pong across tiles
  float4 av[8];        // act row staging (32 VGPR, live across one MFMA phase)
  bf16v8 gv[4];        // act2 gather staging (16 VGPR)

  auto load_gather = [&](int tt){
    #pragma unroll
    for (int x = 0; x < 4; ++x)
      gv[x] = *(const bf16v8*)(gbase + tt*64 + x*8);
  };
  auto load_av = [&](int tt){
    const int arow = i*NDIM + (jb0 + tt)*64 + w*16 + ln16;
    #pragma unroll
    for (int kk = 0; kk < 4; ++kk){
      const float* ap = act + (size_t)arow*CDIM + kk*32 + quad*8;
      av[2*kk]   = *(const float4*)(ap);
      av[2*kk+1] = *(const float4*)(ap + 4);
    }
  };
  auto store_gather = [&](int buf){
    #pragma unroll
    for (int x = 0; x < 4; ++x)
      *(bf16v8*)&vs[buf][cc*74 + hh*32 + x*8] = gv[x];
  };
  auto make_ag = [&](bf16v8* dst){
    float s = 0.f, s2 = 0.f;
    #pragma unroll
    for (int q2 = 0; q2 < 8; ++q2){
      s  += av[q2].x + av[q2].y + av[q2].z + av[q2].w;
      s2 += av[q2].x*av[q2].x + av[q2].y*av[q2].y + av[q2].z*av[q2].z + av[q2].w*av[q2].w;
    }
    s += __shfl_xor(s,16); s2 += __shfl_xor(s2,16);
    s += __shfl_xor(s,32); s2 += __shfl_xor(s2,32);
    const float mean = s*(1.f/128.f);
    const float rstd = rsqrtf(s2*(1.f/128.f) - mean*mean + 1e-5f);
    #pragma unroll
    for (int kk = 0; kk < 4; ++kk){
      const float4 sc0 = *(const float4*)(lns + kk*32 + quad*8);
      const float4 sc1 = *(const float4*)(lns + kk*32 + quad*8 + 4);
      const float4 of0 = *(const float4*)(lno + kk*32 + quad*8);
      const float4 of1 = *(const float4*)(lno + kk*32 + quad*8 + 4);
      bfu pk;
      pk.u[0] = f2bf((av[2*kk].x   - mean)*rstd*sc0.x + of0.x);
      pk.u[1] = f2bf((av[2*kk].y   - mean)*rstd*sc0.y + of0.y);
      pk.u[2] = f2bf((av[2*kk].z   - mean)*rstd*sc0.z + of0.z);
      pk.u[3] = f2bf((av[2*kk].w   - mean)*rstd*sc0.w + of0.w);
      pk.u[4] = f2bf((av[2*kk+1].x - mean)*rstd*sc1.x + of1.x);
      pk.u[5] = f2bf((av[2*kk+1].y - mean)*rstd*sc1.y + of1.y);
      pk.u[6] = f2bf((av[2*kk+1].z - mean)*rstd*sc1.z + of1.z);
      pk.u[7] = f2bf((av[2*kk+1].w - mean)*rstd*sc1.w + of1.w);
      dst[kk] = pk.v;
    }
  };
  auto make_af = [&](const u16* vsb, bf16v8* dst){
    const int jj = w*16 + ln16;
    float s = 0.f, s2 = 0.f;
    #pragma unroll
    for (int kk = 0; kk < 4; ++kk)
      #pragma unroll
      for (int e = 0; e < 8; ++e){
        const float v = bf2f(vsb[(kk*32 + quad*8 + e)*74 + jj]);
        s += v; s2 += v*v;
      }
    s += __shfl_xor(s,16); s2 += __shfl_xor(s2,16);
    s += __shfl_xor(s,32); s2 += __shfl_xor(s2,32);
    const float mean = s*(1.f/128.f);
    const float rstd = rsqrtf(s2*(1.f/128.f) - mean*mean + 1e-5f);
    #pragma unroll
    for (int kk = 0; kk < 4; ++kk){
      const float4 sc0 = *(const float4*)(cns + kk*32 + quad*8);
      const float4 sc1 = *(const float4*)(cns + kk*32 + quad*8 + 4);
      const float4 of0 = *(const float4*)(cno + kk*32 + quad*8);
      const float4 of1 = *(const float4*)(cno + kk*32 + quad*8 + 4);
      bfu pk;
      #pragma unroll
      for (int e = 0; e < 4; ++e){
        const float v = bf2f(vsb[(kk*32 + quad*8 + e)*74 + jj]);
        const float sc = (e==0)?sc0.x:(e==1)?sc0.y:(e==2)?sc0.z:sc0.w;
        const float of = (e==0)?of0.x:(e==1)?of0.y:(e==2)?of0.z:of0.w;
        pk.u[e] = f2bf((v - mean)*rstd*sc + of);
      }
      #pragma unroll
      for (int e = 0; e < 4; ++e){
        const float v = bf2f(vsb[(kk*32 + quad*8 + 4 + e)*74 + jj]);
        const float sc = (e==0)?sc1.x:(e==1)?sc1.y:(e==2)?sc1.z:sc1.w;
        const float of = (e==0)?of1.x:(e==1)?of1.y:(e==2)?of1.z:of1.w;
        pk.u[4+e] = f2bf((v - mean)*rstd*sc + of);
      }
      dst[kk] = pk.v;
    }
  };

  // ---- prologue: tile 0 ----
  load_gather(0);
  load_av(0);
  store_gather(0);          // vmcnt wait lands here (unavoidable once)
  make_ag(ag[0]);
  __syncthreads();

  const f32x4 zero4 = {0.f,0.f,0.f,0.f};
  #pragma unroll
  for (int tt = 0; tt < 4; ++tt){
    if (tt < 3){            // issue next tile's loads; they land during MFMA
      load_gather(tt + 1);
      load_av(tt + 1);
    }
    bf16v8 af[4];
    make_af(vs[tt & 1], af);

    const int m0 = i*NDIM + (jb0 + tt)*64;
    #pragma unroll
    for (int n = 0; n < 8; ++n){
      const u16* wr  = wt + (size_t)(640 + n*16 + ln16)*CDIM + quad*8;  // w_out
      const u16* wgr = wt + (size_t)(512 + n*16 + ln16)*CDIM + quad*8;  // w_gate_out
      bf16v8 bb[4], bg[4];
      #pragma unroll
      for (int kk = 0; kk < 4; ++kk){
        bb[kk] = *(const bf16v8*)(wr  + kk*32);
        bg[kk] = *(const bf16v8*)(wgr + kk*32);
      }
      f32x4 ao = zero4, agg = zero4;
      #pragma unroll
      for (int kk = 0; kk < 4; ++kk){
        ao  = mfma_bf16(af[kk], bb[kk], ao);
        agg = mfma_bf16(ag[tt & 1][kk], bg[kk], agg);
      }
      const int e = n*16 + ln16;
      const float bias = bo[e], bge = bgo[e];
      #pragma unroll
      for (int reg = 0; reg < 4; ++reg){
        const int jl = w*16 + quad*4 + reg;
        out[((size_t)(m0 + jl))*(size_t)CDIM + e] =
            (ao[reg] + bias) * sigm(agg[reg] + bge);
      }
    }

    if (tt < 3){
      store_gather((tt + 1) & 1);   // loads have had the whole MFMA phase
      make_ag(ag[(tt + 1) & 1]);
      __syncthreads();
    }
  }
}

// ---------------------------------------------------------------------------
extern "C" void kernel_launch(void* const* d_in, const int* in_sizes, int n_in,
                              void* d_out, int out_size, void* d_ws, size_t ws_size,
                              hipStream_t stream)
{
  const float* act = (const float*)d_in[0];
  const float* msk = (const float*)d_in[1];
  const float* lns = (const float*)d_in[2];
  const float* lno = (const float*)d_in[3];
  const float* wp  = (const float*)d_in[4];
  const float* wg  = (const float*)d_in[5];
  const float* cns = (const float*)d_in[6];
  const float* cno = (const float*)d_in[7];
  const float* wo  = (const float*)d_in[8];
  const float* bo  = (const float*)d_in[9];
  const float* wgo = (const float*)d_in[10];
  const float* bgo = (const float*)d_in[11];
  float* out = (float*)d_out;

  // ws layout: AB (256*M bf16, 128 MiB) | ACT2 (128*M bf16, 64 MiB) | WT (768*128 bf16)
  u16* AB   = (u16*)d_ws;
  u16* ACT2 = AB + (size_t)256*MDIM;
  u16* WT   = ACT2 + (size_t)128*MDIM;

  k0_prep   <<<dim3(768),  dim3(128), 0, stream>>>(wp, wg, wgo, wo, WT);
  k1_ln_proj<<<dim3(4096), dim3(256), 0, stream>>>(act, msk, lns, lno, WT, AB);
  k2_tri    <<<dim3(2048), dim3(256), 0, stream>>>(AB, ACT2);
  k3_out    <<<dim3(1024), dim3(256), 0, stream>>>(ACT2, WT, act, lns, lno,
                                                   cns, cno, bo, bgo, out);
}